// Round 9
// baseline (624.514 us; speedup 1.0000x reference)
//
#include <hip/hip_runtime.h>
#include <hip/hip_bf16.h>
#include <math.h>

#define BB 32
#define TT 2048
#define DM 512
#define SS 64
#define BT (BB*TT)
#define NSTEPS 4
#define SCALE 0.044194173824159216f

typedef unsigned short u16;
typedef unsigned int u32;
typedef __attribute__((ext_vector_type(8))) short s16x8;
typedef __attribute__((ext_vector_type(4))) float f32x4;
typedef __attribute__((ext_vector_type(4))) unsigned u32x4;

__device__ __forceinline__ u16 f2b(float x){
  __hip_bfloat16 h = __float2bfloat16(x);
  return *reinterpret_cast<u16*>(&h);
}
__device__ __forceinline__ float b2f(u16 u){
  __hip_bfloat16 h;
  *reinterpret_cast<u16*>(&h) = u;
  return __bfloat162float(h);
}

static __device__ __forceinline__ float wave_reduce_sum(float v){
  #pragma unroll
  for (int off=32; off; off>>=1) v += __shfl_down(v, off);
  return v;
}

// ---------------- embedding + token LN (bf16 out), wave-per-row ----------------
__global__ __launch_bounds__(256) void embed_ln_k(const int* __restrict__ ids,
    const float* __restrict__ temb, const float* __restrict__ pemb,
    const float* __restrict__ g, const float* __restrict__ be, u16* __restrict__ out){
  int row = blockIdx.x*4 + (threadIdx.x>>6);
  int l = threadIdx.x & 63;
  int t = row & (TT-1);
  int id = ids[row];
  const float* te = temb + (size_t)id*DM + l*8;
  const float* pe = pemb + (size_t)t*DM + l*8;
  float4 a0 = *(const float4*)te,     a1 = *(const float4*)(te+4);
  float4 p0 = *(const float4*)pe,     p1 = *(const float4*)(pe+4);
  float x[8] = {a0.x+p0.x, a0.y+p0.y, a0.z+p0.z, a0.w+p0.w,
                a1.x+p1.x, a1.y+p1.y, a1.z+p1.z, a1.w+p1.w};
  float s1 = 0.f, s2 = 0.f;
  #pragma unroll
  for (int e=0;e<8;e++){ s1 += x[e]; s2 += x[e]*x[e]; }
  #pragma unroll
  for (int off=1; off<64; off<<=1){ s1 += __shfl_xor(s1, off); s2 += __shfl_xor(s2, off); }
  float mu = s1*(1.f/DM);
  float var = s2*(1.f/DM) - mu*mu;
  float rs = rsqrtf(var + 1e-5f);
  const float* gp = g + l*8;
  const float* bp = be + l*8;
  float4 g0=*(const float4*)gp, g1=*(const float4*)(gp+4);
  float4 b0=*(const float4*)bp, b1=*(const float4*)(bp+4);
  float gg[8]={g0.x,g0.y,g0.z,g0.w,g1.x,g1.y,g1.z,g1.w};
  float bb[8]={b0.x,b0.y,b0.z,b0.w,b1.x,b1.y,b1.z,b1.w};
  s16x8 o;
  #pragma unroll
  for (int e=0;e<8;e++) o[e] = (short)f2b((x[e]-mu)*rs*gg[e] + bb[e]);
  *(s16x8*)(out + (size_t)row*DM + l*8) = o;
}

// ---------------- generic NT bf16 MFMA gemm: C[M][512] = A[M][512] @ Bm[512][512]^T ----------------
// EPI: 2 = f32( b2f(mul[m,n]) * sigmoid(acc+bias[n]) ) ; 3 = f32(acc+bias[n]) ;
//      5 = bf16(acc + rowv[m]*bias[n] + bias2[n])
template<int EPI>
__global__ __launch_bounds__(128) void ntgemm_k(const u16* __restrict__ A,
    const u16* __restrict__ Bm, const float* __restrict__ bias,
    const u16* __restrict__ mulb, const float* __restrict__ rowv,
    const float* __restrict__ bias2, void* __restrict__ Cout, float scalep){
  int m0 = blockIdx.x*32 + (threadIdx.x>>6)*16;
  int n0 = blockIdx.y*64;
  int l = threadIdx.x & 63;
  int lr = l & 15, lk = (l>>4)*8;
  const u16* Arow = A + (size_t)(m0 + lr)*512 + lk;
  const u16* B0   = Bm + (size_t)(n0 + lr)*512 + lk;
  f32x4 acc[4] = {};
  #pragma unroll
  for (int k0=0;k0<512;k0+=32){
    s16x8 a = *(const s16x8*)(Arow + k0);
    #pragma unroll
    for (int j=0;j<4;j++){
      s16x8 b = *(const s16x8*)(B0 + (size_t)j*16*512 + k0);
      acc[j] = __builtin_amdgcn_mfma_f32_16x16x32_bf16(a, b, acc[j], 0,0,0);
    }
  }
  int mbase = m0 + (l>>4)*4;
  #pragma unroll
  for (int j=0;j<4;j++){
    int n = n0 + j*16 + lr;
    #pragma unroll
    for (int r=0;r<4;r++){
      int m = mbase + r;
      float v = acc[j][r];
      if (EPI==2){
        float z = v + bias[n];
        float sg = 1.f/(1.f + expf(-z));
        ((float*)Cout)[(size_t)m*512 + n] = b2f(mulb[(size_t)m*512 + n]) * sg;
      }
      if (EPI==3){ ((float*)Cout)[(size_t)m*512 + n] = v + bias[n]; }
      if (EPI==5){ ((u16*)Cout)[(size_t)m*512 + n] = f2b(v + rowv[m]*bias[n] + bias2[n]); }
    }
  }
}

// ---------------- Pt gemm (y<8) + cb rows (y==8) fused ----------------
__global__ __launch_bounds__(128) void ptcb_k(const u16* __restrict__ A,
    const u16* __restrict__ Bm, const float* __restrict__ bias,
    const float* __restrict__ mem, const float* __restrict__ wcb,
    const float* __restrict__ cb0p, u16* __restrict__ Pt, float* __restrict__ cb){
  int l = threadIdx.x & 63;
  if (blockIdx.y < 8){
    int m0 = blockIdx.x*32 + (threadIdx.x>>6)*16;
    int n0 = blockIdx.y*64;
    int lr = l & 15, lk = (l>>4)*8;
    const u16* Arow = A + (size_t)(m0 + lr)*512 + lk;
    const u16* B0   = Bm + (size_t)(n0 + lr)*512 + lk;
    f32x4 acc[4] = {};
    #pragma unroll
    for (int k0=0;k0<512;k0+=32){
      s16x8 a = *(const s16x8*)(Arow + k0);
      #pragma unroll
      for (int j=0;j<4;j++){
        s16x8 b = *(const s16x8*)(B0 + (size_t)j*16*512 + k0);
        acc[j] = __builtin_amdgcn_mfma_f32_16x16x32_bf16(a, b, acc[j], 0,0,0);
      }
    }
    int mbase = m0 + (l>>4)*4;
    #pragma unroll
    for (int j=0;j<4;j++){
      int n = n0 + j*16 + lr;
      #pragma unroll
      for (int r=0;r<4;r++)
        Pt[(size_t)(mbase+r)*512 + n] = f2b(acc[j][r] + bias[n]);
    }
  } else {
    int base = blockIdx.x*32 + (threadIdx.x>>6)*16;
    for (int i=0;i<16;i++){
      int row = base + i;
      const float* r = mem + (size_t)row*512;
      float s = 0.f;
      #pragma unroll
      for (int k=0;k<8;k++) s += r[l + 64*k]*wcb[l + 64*k];
      #pragma unroll
      for (int off=32; off; off>>=1) s += __shfl_xor(s, off);
      if (l==0) cb[row] = s + cb0p[0];
    }
  }
}

// ---------------- fused scores + top8 softmax binding + colsum partial ----------------
__global__ __launch_bounds__(64) void bind_k(const u16* __restrict__ tok,
    const u16* __restrict__ Pt, const float* __restrict__ cbuf, const int* __restrict__ mask,
    u16* __restrict__ BNDT, float* __restrict__ cspart){
  int b = blockIdx.y, t0 = blockIdx.x*64;
  int l = threadIdx.x;
  int lr = l&15, g = l>>4, lk = g*8;
  __shared__ float sc[64*66];
  __shared__ u16 bt[64*66];

  const u16* Abase = tok + ((size_t)(b*TT + t0 + lr))*512 + lk;
  const u16* Bbase = Pt + ((size_t)(b*SS + lr))*512 + lk;
  f32x4 acc[4][4] = {};
  #pragma unroll
  for (int k0=0;k0<512;k0+=32){
    s16x8 a[4], bb[4];
    #pragma unroll
    for (int mi=0;mi<4;mi++) a[mi] = *(const s16x8*)(Abase + (size_t)mi*16*512 + k0);
    #pragma unroll
    for (int nj=0;nj<4;nj++) bb[nj] = *(const s16x8*)(Bbase + (size_t)nj*16*512 + k0);
    #pragma unroll
    for (int mi=0;mi<4;mi++)
      #pragma unroll
      for (int nj=0;nj<4;nj++)
        acc[mi][nj] = __builtin_amdgcn_mfma_f32_16x16x32_bf16(a[mi], bb[nj], acc[mi][nj], 0,0,0);
  }
  float cbv[4];
  #pragma unroll
  for (int nj=0;nj<4;nj++) cbv[nj] = cbuf[b*SS + 16*nj + lr];
  #pragma unroll
  for (int mi=0;mi<4;mi++)
    #pragma unroll
    for (int nj=0;nj<4;nj++)
      #pragma unroll
      for (int r=0;r<4;r++){
        float x = acc[mi][nj][r] + cbv[nj];
        x = fminf(fmaxf(x, -10.f), 10.f);
        sc[(16*mi + 4*g + r)*66 + 16*nj + lr] = x;
      }

  float sv[64];
  #pragma unroll
  for (int j=0;j<64;j++) sv[j] = sc[l*66 + j];

  u32 work[64];
  #pragma unroll
  for (int j=0;j<64;j++){
    u32 s = __float_as_uint(sv[j]);
    u32 o = s ^ ((u32)(((int)s) >> 31) | 0x80000000u);
    work[j] = (o & 0xFFFFFFC0u) | (u32)(63 - j);
  }
  u32 mtop = 0;
  #pragma unroll
  for (int it=0; it<8; ++it){
    u32 a[32];
    #pragma unroll
    for (int j=0;j<32;j++){ u32 x = work[2*j], y = work[2*j+1]; a[j] = x>y?x:y; }
    #pragma unroll
    for (int lvl=16; lvl>=1; lvl>>=1)
      #pragma unroll
      for (int j=0;j<lvl;j++){ u32 x = a[2*j], y = a[2*j+1]; a[j] = x>y?x:y; }
    u32 m = a[0];
    if (it==0) mtop = m;
    #pragma unroll
    for (int j=0;j<64;j++) work[j] = (work[j]==m) ? 0u : work[j];
  }
  u32 ot = mtop & 0xFFFFFFC0u;
  u32 tb = (ot & 0x80000000u) ? (ot ^ 0x80000000u) : ~ot;
  float T = __uint_as_float(tb);

  float tot = 0.f;
  #pragma unroll
  for (int j=0;j<64;j++){
    float ej = (work[j]==0u) ? expf(sv[j]-T) : 0.f;
    sv[j] = ej;
    tot += ej;
  }
  int mv = mask[b*TT + t0 + l];
  float inv = mv ? 1.f/tot : 0.f;
  #pragma unroll
  for (int j=0;j<64;j++)
    bt[j*66 + l] = f2b(sv[j]*inv);

  const u32* btw = (const u32*)bt;
  u32 rowbuf[32];
  float csum = 0.f;
  #pragma unroll
  for (int w=0;w<32;w++){
    u32 v = btw[l*33 + w];
    rowbuf[w] = v;
    csum += b2f((u16)(v & 0xFFFFu)) + b2f((u16)(v >> 16));
  }
  cspart[((size_t)b*32 + blockIdx.x)*64 + l] = csum;
  u16* dst = BNDT + ((size_t)(b*SS + l))*TT + t0;
  #pragma unroll
  for (int w8=0;w8<8;w8++){
    u32x4 v;
    v[0]=rowbuf[4*w8]; v[1]=rowbuf[4*w8+1]; v[2]=rowbuf[4*w8+2]; v[3]=rowbuf[4*w8+3];
    *(u32x4*)(dst + 8*w8) = v;
  }
}

// ---------------- colsum reduce: slot (clamped), rr, raw ----------------
__global__ __launch_bounds__(64) void csred_k(const float* __restrict__ cspart,
    float* __restrict__ slot, float* __restrict__ rr, float* __restrict__ raw){
  int b = blockIdx.x, s = threadIdx.x;
  float t = 0.f;
  for (int k=0;k<32;k++) t += cspart[((size_t)b*32 + k)*64 + s];
  raw[b*SS+s] = t;
  float sl = fmaxf(t, 1e-6f);
  slot[b*SS+s] = sl;
  rr[b*SS+s] = t/sl;
}

// ---------------- fused wt + /slot -> bf16: t1h[b*64+s][d] ----------------
// grid (8 dgrps of 64 d, 32 b); block loops full T, accumulating in MFMA regs.
__global__ __launch_bounds__(256) void wtfused_k(const u16* __restrict__ BNDT,
    const u16* __restrict__ tok, const float* __restrict__ slot, u16* __restrict__ t1h){
  int dgrp = blockIdx.x, b = blockIdx.y;
  int tid = threadIdx.x, w = tid>>6, l = tid&63;
  int lr = l&15, lk = (l>>4)*8;
  __shared__ u16 tk[64][72];
  f32x4 acc[4] = {};
  int trow = tid>>2, dcol = (tid&3)*16;
  const u16* tokbase = tok + ((size_t)b*TT)*512 + dgrp*64;
  const u16* Abase = BNDT + ((size_t)(b*SS + 16*w + lr))*TT;
  for (int tb=0; tb<TT; tb+=64){
    const u16* src = tokbase + (size_t)(tb + trow)*512 + dcol;
    s16x8 v0 = *(const s16x8*)(src);
    s16x8 v1 = *(const s16x8*)(src+8);
    #pragma unroll
    for (int e=0;e<8;e++){
      int d0 = dcol+e, d1 = dcol+8+e;
      tk[d0][(trow + 8*((d0>>5)&1)) & 63] = (u16)v0[e];
      tk[d1][(trow + 8*((d1>>5)&1)) & 63] = (u16)v1[e];
    }
    __syncthreads();
    #pragma unroll
    for (int kst=0;kst<2;kst++){
      s16x8 a = *(const s16x8*)(Abase + tb + kst*32 + lk);
      #pragma unroll
      for (int nt=0;nt<4;nt++){
        int dd = nt*16 + lr;
        int cb2 = (kst*32 + lk + 8*((dd>>5)&1)) & 63;
        s16x8 bb = *(const s16x8*)&tk[dd][cb2];
        acc[nt] = __builtin_amdgcn_mfma_f32_16x16x32_bf16(a, bb, acc[nt], 0,0,0);
      }
    }
    __syncthreads();
  }
  #pragma unroll
  for (int nt=0;nt<4;nt++){
    int d = dgrp*64 + nt*16 + lr;
    #pragma unroll
    for (int r=0;r<4;r++){
      int s = 16*w + (l>>4)*4 + r;
      int row = b*64 + s;
      t1h[(size_t)row*512 + d] = f2b(acc[nt][r] / slot[row]);
    }
  }
}

// ---------------- batched precompute: 5x cast fp32->bf16 ----------------
__global__ __launch_bounds__(256) void allconv_k(
    const float* __restrict__ s0, u16* __restrict__ d0,
    const float* __restrict__ s1, u16* __restrict__ d1,
    const float* __restrict__ s2, u16* __restrict__ d2,
    const float* __restrict__ s3, u16* __restrict__ d3,
    const float* __restrict__ s4, u16* __restrict__ d4){
  int sel = blockIdx.x >> 10;
  int i = (blockIdx.x & 1023)*256 + threadIdx.x;
  const float* s; u16* d;
  if (sel==0){s=s0;d=d0;} else if (sel==1){s=s1;d=d1;} else if (sel==2){s=s2;d=d2;}
  else if (sel==3){s=s3;d=d3;} else {s=s4;d=d4;}
  d[i] = f2b(s[i]);
}

// ---------------- batched precompute: 3x transpose+convert ----------------
__global__ __launch_bounds__(256) void alltconv_k(
    const float* __restrict__ s0, u16* __restrict__ d0,
    const float* __restrict__ s1, u16* __restrict__ d1,
    const float* __restrict__ s2, u16* __restrict__ d2){
  const float* in; u16* out;
  if (blockIdx.z==0){in=s0;out=d0;} else if (blockIdx.z==1){in=s1;out=d1;} else {in=s2;out=d2;}
  __shared__ float t[32][33];
  int c0 = blockIdx.x*32, r0 = blockIdx.y*32;
  int cx = threadIdx.x&31, ry = threadIdx.x>>5;
  #pragma unroll
  for (int i=0;i<4;i++){ int r = ry + i*8; t[r][cx] = in[(size_t)(r0+r)*512 + c0+cx]; }
  __syncthreads();
  #pragma unroll
  for (int i=0;i<4;i++){ int r = ry + i*8; out[(size_t)(c0+r)*512 + r0+cx] = f2b(t[cx][r]); }
}

// ---------------- batched precompute: 3x NT gemm -> bf16(acc*scale) ----------------
__global__ __launch_bounds__(128) void pregemm_k(
    const u16* __restrict__ A0, const u16* __restrict__ B0, u16* __restrict__ C0, float p0,
    const u16* __restrict__ A1, const u16* __restrict__ B1, u16* __restrict__ C1, float p1,
    const u16* __restrict__ A2, const u16* __restrict__ B2, u16* __restrict__ C2, float p2){
  const u16* A; const u16* Bm; u16* C; float sp;
  if (blockIdx.z==0){A=A0;Bm=B0;C=C0;sp=p0;}
  else if (blockIdx.z==1){A=A1;Bm=B1;C=C1;sp=p1;}
  else {A=A2;Bm=B2;C=C2;sp=p2;}
  int m0 = blockIdx.x*32 + (threadIdx.x>>6)*16;
  int n0 = blockIdx.y*64;
  int l = threadIdx.x & 63;
  int lr = l & 15, lk = (l>>4)*8;
  const u16* Arow = A + (size_t)(m0 + lr)*512 + lk;
  const u16* Bp   = Bm + (size_t)(n0 + lr)*512 + lk;
  f32x4 acc[4] = {};
  #pragma unroll
  for (int k0=0;k0<512;k0+=32){
    s16x8 a = *(const s16x8*)(Arow + k0);
    #pragma unroll
    for (int j=0;j<4;j++){
      s16x8 b = *(const s16x8*)(Bp + (size_t)j*16*512 + k0);
      acc[j] = __builtin_amdgcn_mfma_f32_16x16x32_bf16(a, b, acc[j], 0,0,0);
    }
  }
  int mbase = m0 + (l>>4)*4;
  #pragma unroll
  for (int j=0;j<4;j++){
    int n = n0 + j*16 + lr;
    #pragma unroll
    for (int r=0;r<4;r++)
      C[(size_t)(mbase+r)*512 + n] = f2b(acc[j][r] * sp);
  }
}

// ---------------- batched precompute: 4x matvec + bvw + dot2 ----------------
__global__ __launch_bounds__(256) void smalls_k(
    const float* __restrict__ qW, const float* __restrict__ kB, float* __restrict__ bq,
    const float* __restrict__ rqW, const float* __restrict__ rkB, float* __restrict__ bq_r,
    const float* __restrict__ kW, const float* __restrict__ qB, float* __restrict__ wcb,
    const float* __restrict__ rkW, const float* __restrict__ rqB, float* __restrict__ wcb_r,
    const float* __restrict__ wrW, const float* __restrict__ vB, float* __restrict__ bvw,
    float* __restrict__ cb0s){
  int blk = blockIdx.x;
  if (blk < 512){
    int which = blk >> 7;
    const float* W; const float* v; float* out;
    if (which==0){W=qW; v=kB; out=bq;}
    else if (which==1){W=rqW; v=rkB; out=bq_r;}
    else if (which==2){W=kW; v=qB; out=wcb;}
    else {W=rkW; v=rqB; out=wcb_r;}
    int i = (blk&127)*4 + (threadIdx.x>>6), l = threadIdx.x&63;
    const float* r = W + (size_t)i*512;
    float s = 0.f;
    #pragma unroll
    for (int k=0;k<8;k++) s += r[l + 64*k]*v[l + 64*k];
    #pragma unroll
    for (int off=32; off; off>>=1) s += __shfl_xor(s, off);
    if (l==0) out[i] = s * SCALE;
  } else if (blk < 514){
    int n = (blk-512)*256 + threadIdx.x;
    float s = 0.f;
    for (int o=0;o<512;o++) s += vB[o]*wrW[(size_t)o*512 + n];
    bvw[n] = s;
  } else {
    if (threadIdx.x < 128){
      int w = threadIdx.x>>6, l = threadIdx.x&63;
      const float* a = w ? rkB : kB;
      const float* bvec = w ? rqB : qB;
      float s = 0.f;
      #pragma unroll
      for (int k=0;k<8;k++) s += a[l + 64*k]*bvec[l + 64*k];
      #pragma unroll
      for (int off=32; off; off>>=1) s += __shfl_xor(s, off);
      if (l==0) cb0s[w] = s * SCALE;
    }
  }
}

// ---------------- memory init (fp32 + bf16 mirror) ----------------
__global__ __launch_bounds__(256) void meminit_k(const float* __restrict__ src,
    float* __restrict__ mem, u16* __restrict__ memh){
  int i = blockIdx.x*256 + threadIdx.x;
  float v = src[i & (SS*DM-1)];
  mem[i] = v;
  memh[i] = f2b(v);
}

// ---------------- mem = LN(0.9*mem + 0.1*w3) -> fp32 + bf16 mirror ----------------
__global__ __launch_bounds__(256) void mem_ln_k(float* __restrict__ mem, const float* __restrict__ w3,
    const float* __restrict__ g, const float* __restrict__ be, u16* __restrict__ memh){
  int row = blockIdx.x;
  int d = threadIdx.x;
  float* mrow = mem + (size_t)row*DM;
  const float* wrow = w3 + (size_t)row*DM;
  float x0 = 0.9f*mrow[d]     + 0.1f*wrow[d];
  float x1 = 0.9f*mrow[d+256] + 0.1f*wrow[d+256];
  float s1 = x0+x1, s2 = x0*x0 + x1*x1;
  s1 = wave_reduce_sum(s1); s2 = wave_reduce_sum(s2);
  __shared__ float r1[4], r2[4];
  int lane = d & 63, w = d>>6;
  if (lane==0){ r1[w]=s1; r2[w]=s2; }
  __syncthreads();
  float S1 = r1[0]+r1[1]+r1[2]+r1[3];
  float S2 = r2[0]+r2[1]+r2[2]+r2[3];
  float mu = S1 * (1.f/DM);
  float var = S2*(1.f/DM) - mu*mu;
  float rs = rsqrtf(var + 1e-5f);
  float y0 = (x0-mu)*rs*g[d] + be[d];
  float y1 = (x1-mu)*rs*g[d+256] + be[d+256];
  mrow[d] = y0; mrow[d+256] = y1;
  memh[(size_t)row*DM + d] = f2b(y0);
  memh[(size_t)row*DM + d+256] = f2b(y1);
}

// ---------------- masked token sum partials (vectorized, per-wave slices) ----------------
__global__ __launch_bounds__(256) void tokpart_k(const u16* __restrict__ tok,
    const int* __restrict__ mask, float* __restrict__ tp){
  int b = blockIdx.x, sl = blockIdx.y;
  int w = threadIdx.x>>6, l = threadIdx.x&63;
  float acc[8] = {};
  #pragma unroll 4
  for (int i=0;i<32;i++){
    int t = sl*128 + w + 4*i;
    float m = (float)mask[b*TT + t];
    s16x8 v = *(const s16x8*)(tok + ((size_t)(b*TT + t))*512 + l*8);
    #pragma unroll
    for (int e=0;e<8;e++) acc[e] += m*b2f((u16)v[e]);
  }
  float* dst = tp + ((size_t)(b*64 + sl*4 + w))*512 + l*8;
  #pragma unroll
  for (int e=0;e<8;e++) dst[e] = acc[e];
}

// ---------------- catden: cat[b][1024] = [tok_sum, ctx], denom[b] ----------------
__global__ __launch_bounds__(256) void catden_k(const float* __restrict__ tp,
    const float* __restrict__ rws, const float* __restrict__ rv,
    const int* __restrict__ mask, float* __restrict__ cat, float* __restrict__ denomv){
  int b = blockIdx.x, tid = threadIdx.x;
  float dn = 0.f;
  for (int t=tid; t<TT; t+=256) dn += (float)mask[b*TT+t];
  dn = wave_reduce_sum(dn);
  __shared__ float dred[4];
  if ((tid&63)==0) dred[tid>>6]=dn;
  #pragma unroll
  for (int it=0; it<2; ++it){
    int d = tid + it*256;
    float ts = 0.f;
    for (int k=0;k<64;k++) ts += tp[((size_t)(b*64+k))*512 + d];
    cat[(size_t)b*1024 + d] = ts;
    float c = 0.f;
    for (int s=0;s<SS;s++) c += rws[b*SS+s]*rv[((size_t)b*SS+s)*DM + d];
    cat[(size_t)b*1024 + 512 + d] = c;
  }
  __syncthreads();
  if (tid==0) denomv[b] = dred[0]+dred[1]+dred[2]+dred[3];
}

// ---------------- fuse: pooled[b][n0..n0+64] ----------------
__global__ __launch_bounds__(256) void fuse_k(const float* __restrict__ cat,
    const float* __restrict__ denomv, const float* __restrict__ fuseW,
    const float* __restrict__ fuseb, float* __restrict__ pooled){
  int b = blockIdx.x, n0 = blockIdx.y*64;
  int l = threadIdx.x&63, kc = threadIdx.x>>6;
  int n = n0 + l;
  float acc = 0.f;
  const float* crow = cat + (size_t)b*1024;
  for (int k=kc*256; k<kc*256+256; ++k)
    acc += crow[k]*fuseW[(size_t)k*512 + n];
  __shared__ float red[4][64];
  red[kc][l] = acc;
  __syncthreads();
  if (kc==0){
    float denom = denomv[b];
    float tot = red[0][l]+red[1][l]+red[2][l]+red[3][l];
    pooled[(size_t)b*512 + n] = (tot + denom*fuseb[n]) / fmaxf(denom, 1.f);
  }
}

// ---------------- cls: out[b][8] ----------------
__global__ __launch_bounds__(256) void cls_k(const float* __restrict__ pooled,
    const float* __restrict__ clsW, const float* __restrict__ clsb, float* __restrict__ out){
  int b = blockIdx.x;
  int c = threadIdx.x&7, kc = threadIdx.x>>3;
  float acc = 0.f;
  const float* prow = pooled + (size_t)b*512;
  for (int d=kc*16; d<kc*16+16; ++d) acc += prow[d]*clsW[d*8+c];
  __shared__ float red[32][8];
  red[kc][c] = acc;
  __syncthreads();
  if (threadIdx.x < 8){
    float tot = 0.f;
    #pragma unroll
    for (int k=0;k<32;k++) tot += red[k][threadIdx.x];
    out[b*8 + threadIdx.x] = tot + clsb[threadIdx.x];
  }
}

extern "C" void kernel_launch(void* const* d_in, const int* in_sizes, int n_in,
                              void* d_out, int out_size, void* d_ws, size_t ws_size,
                              hipStream_t stream){
  (void)in_sizes; (void)n_in; (void)out_size; (void)ws_size;
  const int*   ids   = (const int*)d_in[0];
  const int*   amask = (const int*)d_in[1];
  const float* temb  = (const float*)d_in[2];
  const float* pemb  = (const float*)d_in[3];
  const float* mem0  = (const float*)d_in[4];
  const float* qW=(const float*)d_in[5],  *qB=(const float*)d_in[6];
  const float* kW=(const float*)d_in[7],  *kB=(const float*)d_in[8];
  const float* vW=(const float*)d_in[9],  *vB=(const float*)d_in[10];
  const float* wrW=(const float*)d_in[11],*wrB=(const float*)d_in[12];
  const float* gtW=(const float*)d_in[13],*gtB=(const float*)d_in[14];
  const float* rqW=(const float*)d_in[15],*rqB=(const float*)d_in[16];
  const float* rkW=(const float*)d_in[17],*rkB=(const float*)d_in[18];
  const float* rvW=(const float*)d_in[19],*rvB=(const float*)d_in[20];
  const float* fW=(const float*)d_in[21], *fB=(const float*)d_in[22];
  const float* cW=(const float*)d_in[23], *cB=(const float*)d_in[24];
  const float* tg=(const float*)d_in[25], *tb=(const float*)d_in[26];
  const float* mg=(const float*)d_in[27], *mb=(const float*)d_in[28];

  // ---- workspace layout (~108 MB) ----
  char* p = (char*)d_ws;
  size_t off = 0;
  auto alloc = [&](size_t bytes)->char*{ char* r = p + off; off += (bytes + 255) & ~(size_t)255; return r; };
  u16*   tokens = (u16*)  alloc((size_t)BT*DM*2);        // 67.1 MB
  u16*   Pt     = (u16*)  alloc((size_t)BB*SS*DM*2);     // 2.1 MB
  u16*   BNDT   = (u16*)  alloc((size_t)BB*SS*TT*2);     // 8.4 MB
  float* cspart = (float*)alloc((size_t)BB*32*64*4);     // 0.26 MB
  float* scratch= (float*)alloc((size_t)4*2048*512*4);   // 16.8 MB (hosts aliases)
  u16*   t1h    = (u16*)  alloc((size_t)2048*512*2);
  u16*   zh     = (u16*)  alloc((size_t)2048*512*2);
  float* mem    = (float*)alloc((size_t)BB*SS*DM*4);
  u16*   memh   = (u16*)  alloc((size_t)BB*SS*DM*2);
  u16*   wrWT   = (u16*)  alloc(512*512*2);
  u16*   gtWT   = (u16*)  alloc(512*512*2);
  u16*   rvWT   = (u16*)  alloc(512*512*2);
  u16*   WqkT   = (u16*)  alloc(512*512*2);
  u16*   WqkT_r = (u16*)  alloc(512*512*2);
  u16*   WvwT   = (u16*)  alloc(512*512*2);
  float* bq     = (float*)alloc(512*4);
  float* bq_r   = (float*)alloc(512*4);
  float* wcb    = (float*)alloc(512*4);
  float* wcb_r  = (float*)alloc(512*4);
  float* bvw    = (float*)alloc(512*4);
  float* cb0s   = (float*)alloc(256);
  float* cbuf   = (float*)alloc(2048*4);
  float* slot   = (float*)alloc(2048*4);
  float* rr     = (float*)alloc(2048*4);
  float* raw    = (float*)alloc(2048*4);
  float* catbuf = (float*)alloc((size_t)BB*1024*4);
  float* denomv = (float*)alloc(BB*4);
  float* pooled = (float*)alloc((size_t)BB*512*4);
  // aliases inside scratch (liveness-disjoint):
  float* rv32   = scratch;                       // read phase only (4 MB)
  float* tspart = scratch + 1048576;             // read phase only (4 MB)
  float* gh32   = scratch + 2097152;             // step gate output (4 MB)
  u16*   qWb    = (u16*)((char*)scratch + 12582912);  // precompute only
  u16*   kWb    = qWb + 512*512;
  u16*   rqWb   = kWb + 512*512;
  u16*   rkWb   = rqWb + 512*512;
  u16*   vWb    = (u16*)((char*)scratch + 14680064);  // precompute only

  // ---- precompute (6 dispatches) ----
  allconv_k<<<5120, 256, 0, stream>>>(qW, qWb, kW, kWb, rqW, rqWb, rkW, rkWb, vW, vWb);
  alltconv_k<<<dim3(16,16,3), 256, 0, stream>>>(wrW, wrWT, gtW, gtWT, rvW, rvWT);
  pregemm_k<<<dim3(16,8,3), 128, 0, stream>>>(qWb, kWb, WqkT, SCALE,
                                              rqWb, rkWb, WqkT_r, SCALE,
                                              wrWT, vWb, WvwT, 1.0f);
  smalls_k<<<515, 256, 0, stream>>>(qW, kB, bq, rqW, rkB, bq_r, kW, qB, wcb,
                                    rkW, rqB, wcb_r, wrW, vB, bvw, cb0s);
  embed_ln_k<<<BT/4, 256, 0, stream>>>(ids, temb, pemb, tg, tb, tokens);
  meminit_k<<<(BB*SS*DM)/256, 256, 0, stream>>>(mem0, mem, memh);

  // ---- recurrent steps (7 dispatches each) ----
  for (int step=0; step<NSTEPS; ++step){
    ptcb_k<<<dim3(64,9), 128, 0, stream>>>(memh, WqkT, bq, mem, wcb, cb0s, Pt, cbuf);
    bind_k<<<dim3(32,32), 64, 0, stream>>>(tokens, Pt, cbuf, amask, BNDT, cspart);
    csred_k<<<32, 64, 0, stream>>>(cspart, slot, rr, raw);
    wtfused_k<<<dim3(8,32), 256, 0, stream>>>(BNDT, tokens, slot, t1h);
    ntgemm_k<5><<<dim3(64,8), 128, 0, stream>>>(t1h, WvwT, bvw, nullptr, rr, wrB, zh, 0.f);
    ntgemm_k<2><<<dim3(64,8), 128, 0, stream>>>(zh, gtWT, gtB, zh, nullptr, nullptr, gh32, 0.f);
    mem_ln_k<<<BB*SS, 256, 0, stream>>>(mem, gh32, mg, mb, memh);
  }

  // ---- read phase ----
  ptcb_k<<<dim3(64,9), 128, 0, stream>>>(memh, WqkT_r, bq_r, mem, wcb_r, cb0s+1, Pt, cbuf);
  bind_k<<<dim3(32,32), 64, 0, stream>>>(tokens, Pt, cbuf, amask, BNDT, cspart);
  csred_k<<<32, 64, 0, stream>>>(cspart, slot, rr, raw);
  ntgemm_k<3><<<dim3(64,8), 128, 0, stream>>>(memh, rvWT, rvB, nullptr, nullptr, nullptr, rv32, 0.f);
  tokpart_k<<<dim3(32,16), 256, 0, stream>>>(tokens, amask, tspart);
  catden_k<<<32, 256, 0, stream>>>(tspart, raw, rv32, amask, catbuf, denomv);
  fuse_k<<<dim3(32,8), 256, 0, stream>>>(catbuf, denomv, fW, fB, pooled);
  cls_k<<<32, 256, 0, stream>>>(pooled, cW, cB, (float*)d_out);
}

// Round 10
// 569.660 us; speedup vs baseline: 1.0963x; 1.0963x over previous
//
#include <hip/hip_runtime.h>
#include <hip/hip_bf16.h>
#include <math.h>

#define BB 32
#define TT 2048
#define DM 512
#define SS 64
#define BT (BB*TT)
#define NSTEPS 4
#define SCALE 0.044194173824159216f

typedef unsigned short u16;
typedef unsigned int u32;
typedef __attribute__((ext_vector_type(8))) short s16x8;
typedef __attribute__((ext_vector_type(4))) float f32x4;
typedef __attribute__((ext_vector_type(4))) unsigned u32x4;

__device__ __forceinline__ u16 f2b(float x){
  __hip_bfloat16 h = __float2bfloat16(x);
  return *reinterpret_cast<u16*>(&h);
}
__device__ __forceinline__ float b2f(u16 u){
  __hip_bfloat16 h;
  *reinterpret_cast<u16*>(&h) = u;
  return __bfloat162float(h);
}

static __device__ __forceinline__ float wave_reduce_sum(float v){
  #pragma unroll
  for (int off=32; off; off>>=1) v += __shfl_down(v, off);
  return v;
}

// ---------------- embedding + token LN (bf16 out), 2 rows per wave for ILP ----------------
__global__ __launch_bounds__(256) void embed_ln_k(const int* __restrict__ ids,
    const float* __restrict__ temb, const float* __restrict__ pemb,
    const float* __restrict__ g, const float* __restrict__ be, u16* __restrict__ out){
  int w = threadIdx.x>>6, l = threadIdx.x & 63;
  int row0 = blockIdx.x*8 + w*2;
  int row1 = row0 + 1;
  int t0 = row0 & (TT-1), t1 = row1 & (TT-1);
  int id0 = ids[row0], id1 = ids[row1];
  const float* teA = temb + (size_t)id0*DM + l*8;
  const float* peA = pemb + (size_t)t0*DM + l*8;
  const float* teB = temb + (size_t)id1*DM + l*8;
  const float* peB = pemb + (size_t)t1*DM + l*8;
  float4 a0=*(const float4*)teA, a1=*(const float4*)(teA+4);
  float4 c0=*(const float4*)teB, c1=*(const float4*)(teB+4);
  float4 p0=*(const float4*)peA, p1=*(const float4*)(peA+4);
  float4 q0=*(const float4*)peB, q1=*(const float4*)(peB+4);
  float xA[8] = {a0.x+p0.x, a0.y+p0.y, a0.z+p0.z, a0.w+p0.w,
                 a1.x+p1.x, a1.y+p1.y, a1.z+p1.z, a1.w+p1.w};
  float xB[8] = {c0.x+q0.x, c0.y+q0.y, c0.z+q0.z, c0.w+q0.w,
                 c1.x+q1.x, c1.y+q1.y, c1.z+q1.z, c1.w+q1.w};
  float sA1=0.f, sA2=0.f, sB1=0.f, sB2=0.f;
  #pragma unroll
  for (int e=0;e<8;e++){ sA1 += xA[e]; sA2 += xA[e]*xA[e]; sB1 += xB[e]; sB2 += xB[e]*xB[e]; }
  #pragma unroll
  for (int off=1; off<64; off<<=1){
    sA1 += __shfl_xor(sA1, off); sA2 += __shfl_xor(sA2, off);
    sB1 += __shfl_xor(sB1, off); sB2 += __shfl_xor(sB2, off);
  }
  float muA = sA1*(1.f/DM), muB = sB1*(1.f/DM);
  float rsA = rsqrtf(sA2*(1.f/DM) - muA*muA + 1e-5f);
  float rsB = rsqrtf(sB2*(1.f/DM) - muB*muB + 1e-5f);
  const float* gp = g + l*8;
  const float* bp = be + l*8;
  float4 g0=*(const float4*)gp, g1=*(const float4*)(gp+4);
  float4 b0=*(const float4*)bp, b1=*(const float4*)(bp+4);
  float gg[8]={g0.x,g0.y,g0.z,g0.w,g1.x,g1.y,g1.z,g1.w};
  float bb[8]={b0.x,b0.y,b0.z,b0.w,b1.x,b1.y,b1.z,b1.w};
  s16x8 oA, oB;
  #pragma unroll
  for (int e=0;e<8;e++){
    oA[e] = (short)f2b((xA[e]-muA)*rsA*gg[e] + bb[e]);
    oB[e] = (short)f2b((xB[e]-muB)*rsB*gg[e] + bb[e]);
  }
  *(s16x8*)(out + (size_t)row0*DM + l*8) = oA;
  *(s16x8*)(out + (size_t)row1*DM + l*8) = oB;
}

// ---------------- generic NT bf16 MFMA gemm: C[M][512] = A[M][512] @ Bm[512][512]^T ----------------
// EPI: 2 = f32( b2f(mul[m,n]) * sigmoid(acc+bias[n]) ) ; 3 = f32(acc+bias[n]) ;
//      5 = bf16(acc + rowv[m]*bias[n] + bias2[n])
template<int EPI>
__global__ __launch_bounds__(128) void ntgemm_k(const u16* __restrict__ A,
    const u16* __restrict__ Bm, const float* __restrict__ bias,
    const u16* __restrict__ mulb, const float* __restrict__ rowv,
    const float* __restrict__ bias2, void* __restrict__ Cout, float scalep){
  int m0 = blockIdx.x*32 + (threadIdx.x>>6)*16;
  int n0 = blockIdx.y*64;
  int l = threadIdx.x & 63;
  int lr = l & 15, lk = (l>>4)*8;
  const u16* Arow = A + (size_t)(m0 + lr)*512 + lk;
  const u16* B0   = Bm + (size_t)(n0 + lr)*512 + lk;
  f32x4 acc[4] = {};
  #pragma unroll
  for (int k0=0;k0<512;k0+=32){
    s16x8 a = *(const s16x8*)(Arow + k0);
    #pragma unroll
    for (int j=0;j<4;j++){
      s16x8 b = *(const s16x8*)(B0 + (size_t)j*16*512 + k0);
      acc[j] = __builtin_amdgcn_mfma_f32_16x16x32_bf16(a, b, acc[j], 0,0,0);
    }
  }
  int mbase = m0 + (l>>4)*4;
  #pragma unroll
  for (int j=0;j<4;j++){
    int n = n0 + j*16 + lr;
    #pragma unroll
    for (int r=0;r<4;r++){
      int m = mbase + r;
      float v = acc[j][r];
      if (EPI==2){
        float z = v + bias[n];
        float sg = 1.f/(1.f + expf(-z));
        ((float*)Cout)[(size_t)m*512 + n] = b2f(mulb[(size_t)m*512 + n]) * sg;
      }
      if (EPI==3){ ((float*)Cout)[(size_t)m*512 + n] = v + bias[n]; }
      if (EPI==5){ ((u16*)Cout)[(size_t)m*512 + n] = f2b(v + rowv[m]*bias[n] + bias2[n]); }
    }
  }
}

// ---------------- Pt gemm (y<8) + cb rows (y==8) fused ----------------
__global__ __launch_bounds__(128) void ptcb_k(const u16* __restrict__ A,
    const u16* __restrict__ Bm, const float* __restrict__ bias,
    const float* __restrict__ mem, const float* __restrict__ wcb,
    const float* __restrict__ cb0p, u16* __restrict__ Pt, float* __restrict__ cb){
  int l = threadIdx.x & 63;
  if (blockIdx.y < 8){
    int m0 = blockIdx.x*32 + (threadIdx.x>>6)*16;
    int n0 = blockIdx.y*64;
    int lr = l & 15, lk = (l>>4)*8;
    const u16* Arow = A + (size_t)(m0 + lr)*512 + lk;
    const u16* B0   = Bm + (size_t)(n0 + lr)*512 + lk;
    f32x4 acc[4] = {};
    #pragma unroll
    for (int k0=0;k0<512;k0+=32){
      s16x8 a = *(const s16x8*)(Arow + k0);
      #pragma unroll
      for (int j=0;j<4;j++){
        s16x8 b = *(const s16x8*)(B0 + (size_t)j*16*512 + k0);
        acc[j] = __builtin_amdgcn_mfma_f32_16x16x32_bf16(a, b, acc[j], 0,0,0);
      }
    }
    int mbase = m0 + (l>>4)*4;
    #pragma unroll
    for (int j=0;j<4;j++){
      int n = n0 + j*16 + lr;
      #pragma unroll
      for (int r=0;r<4;r++)
        Pt[(size_t)(mbase+r)*512 + n] = f2b(acc[j][r] + bias[n]);
    }
  } else {
    int base = blockIdx.x*32 + (threadIdx.x>>6)*16;
    for (int i=0;i<16;i++){
      int row = base + i;
      const float* r = mem + (size_t)row*512;
      float s = 0.f;
      #pragma unroll
      for (int k=0;k<8;k++) s += r[l + 64*k]*wcb[l + 64*k];
      #pragma unroll
      for (int off=32; off; off>>=1) s += __shfl_xor(s, off);
      if (l==0) cb[row] = s + cb0p[0];
    }
  }
}

// ---------------- fused scores + top8 softmax binding + colsum partial ----------------
__global__ __launch_bounds__(64) void bind_k(const u16* __restrict__ tok,
    const u16* __restrict__ Pt, const float* __restrict__ cbuf, const int* __restrict__ mask,
    u16* __restrict__ BNDT, float* __restrict__ cspart){
  int b = blockIdx.y, t0 = blockIdx.x*64;
  int l = threadIdx.x;
  int lr = l&15, g = l>>4, lk = g*8;
  __shared__ float sc[64*66];
  __shared__ u16 bt[64*66];

  const u16* Abase = tok + ((size_t)(b*TT + t0 + lr))*512 + lk;
  const u16* Bbase = Pt + ((size_t)(b*SS + lr))*512 + lk;
  f32x4 acc[4][4] = {};
  #pragma unroll
  for (int k0=0;k0<512;k0+=32){
    s16x8 a[4], bb[4];
    #pragma unroll
    for (int mi=0;mi<4;mi++) a[mi] = *(const s16x8*)(Abase + (size_t)mi*16*512 + k0);
    #pragma unroll
    for (int nj=0;nj<4;nj++) bb[nj] = *(const s16x8*)(Bbase + (size_t)nj*16*512 + k0);
    #pragma unroll
    for (int mi=0;mi<4;mi++)
      #pragma unroll
      for (int nj=0;nj<4;nj++)
        acc[mi][nj] = __builtin_amdgcn_mfma_f32_16x16x32_bf16(a[mi], bb[nj], acc[mi][nj], 0,0,0);
  }
  float cbv[4];
  #pragma unroll
  for (int nj=0;nj<4;nj++) cbv[nj] = cbuf[b*SS + 16*nj + lr];
  #pragma unroll
  for (int mi=0;mi<4;mi++)
    #pragma unroll
    for (int nj=0;nj<4;nj++)
      #pragma unroll
      for (int r=0;r<4;r++){
        float x = acc[mi][nj][r] + cbv[nj];
        x = fminf(fmaxf(x, -10.f), 10.f);
        sc[(16*mi + 4*g + r)*66 + 16*nj + lr] = x;
      }

  float sv[64];
  #pragma unroll
  for (int j=0;j<64;j++) sv[j] = sc[l*66 + j];

  u32 work[64];
  #pragma unroll
  for (int j=0;j<64;j++){
    u32 s = __float_as_uint(sv[j]);
    u32 o = s ^ ((u32)(((int)s) >> 31) | 0x80000000u);
    work[j] = (o & 0xFFFFFFC0u) | (u32)(63 - j);
  }
  u32 mtop = 0;
  #pragma unroll
  for (int it=0; it<8; ++it){
    u32 a[32];
    #pragma unroll
    for (int j=0;j<32;j++){ u32 x = work[2*j], y = work[2*j+1]; a[j] = x>y?x:y; }
    #pragma unroll
    for (int lvl=16; lvl>=1; lvl>>=1)
      #pragma unroll
      for (int j=0;j<lvl;j++){ u32 x = a[2*j], y = a[2*j+1]; a[j] = x>y?x:y; }
    u32 m = a[0];
    if (it==0) mtop = m;
    #pragma unroll
    for (int j=0;j<64;j++) work[j] = (work[j]==m) ? 0u : work[j];
  }
  u32 ot = mtop & 0xFFFFFFC0u;
  u32 tb = (ot & 0x80000000u) ? (ot ^ 0x80000000u) : ~ot;
  float T = __uint_as_float(tb);

  float tot = 0.f;
  #pragma unroll
  for (int j=0;j<64;j++){
    float ej = (work[j]==0u) ? expf(sv[j]-T) : 0.f;
    sv[j] = ej;
    tot += ej;
  }
  int mv = mask[b*TT + t0 + l];
  float inv = mv ? 1.f/tot : 0.f;
  #pragma unroll
  for (int j=0;j<64;j++)
    bt[j*66 + l] = f2b(sv[j]*inv);

  const u32* btw = (const u32*)bt;
  u32 rowbuf[32];
  float csum = 0.f;
  #pragma unroll
  for (int w=0;w<32;w++){
    u32 v = btw[l*33 + w];
    rowbuf[w] = v;
    csum += b2f((u16)(v & 0xFFFFu)) + b2f((u16)(v >> 16));
  }
  cspart[((size_t)b*32 + blockIdx.x)*64 + l] = csum;
  u16* dst = BNDT + ((size_t)(b*SS + l))*TT + t0;
  #pragma unroll
  for (int w8=0;w8<8;w8++){
    u32x4 v;
    v[0]=rowbuf[4*w8]; v[1]=rowbuf[4*w8+1]; v[2]=rowbuf[4*w8+2]; v[3]=rowbuf[4*w8+3];
    *(u32x4*)(dst + 8*w8) = v;
  }
}

// ---------------- colsum reduce: slot (clamped), rr, raw ----------------
__global__ __launch_bounds__(64) void csred_k(const float* __restrict__ cspart,
    float* __restrict__ slot, float* __restrict__ rr, float* __restrict__ raw){
  int b = blockIdx.x, s = threadIdx.x;
  float t = 0.f;
  for (int k=0;k<32;k++) t += cspart[((size_t)b*32 + k)*64 + s];
  raw[b*SS+s] = t;
  float sl = fmaxf(t, 1e-6f);
  slot[b*SS+s] = sl;
  rr[b*SS+s] = t/sl;
}

// ---------------- wt: part[ks][b*64+s][d] = sum_{t in slice} BNDT[b,s,t]*tok[b,t,d] ----------------
__global__ __launch_bounds__(256) void wt_k(const u16* __restrict__ BNDT,
    const u16* __restrict__ tok, float* __restrict__ part){
  int dgrp = blockIdx.x, b = blockIdx.y, ks = blockIdx.z;
  int tid = threadIdx.x, w = tid>>6, l = tid&63;
  int lr = l&15, lk = (l>>4)*8;
  __shared__ u16 tk[128][72];
  f32x4 acc[8] = {};
  int trow = tid>>2, dseg = (tid&3)*32;
  const u16* tokbase = tok + ((size_t)b*TT)*512 + dgrp*128;
  const u16* Abase = BNDT + ((size_t)(b*SS + 16*w + lr))*TT;
  for (int chunk=0; chunk<8; ++chunk){
    int tb = ks*512 + chunk*64;
    const u16* src = tokbase + (size_t)(tb + trow)*512 + dseg;
    s16x8 v0 = *(const s16x8*)(src);
    s16x8 v1 = *(const s16x8*)(src+8);
    s16x8 v2 = *(const s16x8*)(src+16);
    s16x8 v3 = *(const s16x8*)(src+24);
    #pragma unroll
    for (int e=0;e<8;e++){
      int d0 = dseg+e, d1 = dseg+8+e, d2 = dseg+16+e, d3 = dseg+24+e;
      tk[d0][(trow + 8*((d0>>5)&3)) & 63] = (u16)v0[e];
      tk[d1][(trow + 8*((d1>>5)&3)) & 63] = (u16)v1[e];
      tk[d2][(trow + 8*((d2>>5)&3)) & 63] = (u16)v2[e];
      tk[d3][(trow + 8*((d3>>5)&3)) & 63] = (u16)v3[e];
    }
    __syncthreads();
    #pragma unroll
    for (int kst=0;kst<2;kst++){
      s16x8 a = *(const s16x8*)(Abase + tb + kst*32 + lk);
      #pragma unroll
      for (int nt=0;nt<8;nt++){
        int dd = nt*16 + lr;
        int cb2 = (kst*32 + lk + 8*((dd>>5)&3)) & 63;
        s16x8 bb = *(const s16x8*)&tk[dd][cb2];
        acc[nt] = __builtin_amdgcn_mfma_f32_16x16x32_bf16(a, bb, acc[nt], 0,0,0);
      }
    }
    __syncthreads();
  }
  float* dst = part + (size_t)ks*2048*512 + ((size_t)(b*SS))*512 + dgrp*128;
  #pragma unroll
  for (int nt=0;nt<8;nt++){
    int d = nt*16 + lr;
    #pragma unroll
    for (int r=0;r<4;r++){
      int s = 16*w + (l>>4)*4 + r;
      dst[(size_t)s*512 + d] = acc[nt][r];
    }
  }
}

// ---------------- wt reduce + /slot -> bf16 ----------------
__global__ __launch_bounds__(256) void wtred_k(const float* __restrict__ part,
    const float* __restrict__ slot, u16* __restrict__ t1h){
  int i = blockIdx.x*256 + threadIdx.x;
  int row = i>>9;
  float v = part[i] + part[i + 2048*512] + part[i + 2*2048*512] + part[i + 3*2048*512];
  t1h[i] = f2b(v / slot[row]);
}

// ---------------- batched precompute: 5x cast fp32->bf16 ----------------
__global__ __launch_bounds__(256) void allconv_k(
    const float* __restrict__ s0, u16* __restrict__ d0,
    const float* __restrict__ s1, u16* __restrict__ d1,
    const float* __restrict__ s2, u16* __restrict__ d2,
    const float* __restrict__ s3, u16* __restrict__ d3,
    const float* __restrict__ s4, u16* __restrict__ d4){
  int sel = blockIdx.x >> 10;
  int i = (blockIdx.x & 1023)*256 + threadIdx.x;
  const float* s; u16* d;
  if (sel==0){s=s0;d=d0;} else if (sel==1){s=s1;d=d1;} else if (sel==2){s=s2;d=d2;}
  else if (sel==3){s=s3;d=d3;} else {s=s4;d=d4;}
  d[i] = f2b(s[i]);
}

// ---------------- batched precompute: 3x transpose+convert ----------------
__global__ __launch_bounds__(256) void alltconv_k(
    const float* __restrict__ s0, u16* __restrict__ d0,
    const float* __restrict__ s1, u16* __restrict__ d1,
    const float* __restrict__ s2, u16* __restrict__ d2){
  const float* in; u16* out;
  if (blockIdx.z==0){in=s0;out=d0;} else if (blockIdx.z==1){in=s1;out=d1;} else {in=s2;out=d2;}
  __shared__ float t[32][33];
  int c0 = blockIdx.x*32, r0 = blockIdx.y*32;
  int cx = threadIdx.x&31, ry = threadIdx.x>>5;
  #pragma unroll
  for (int i=0;i<4;i++){ int r = ry + i*8; t[r][cx] = in[(size_t)(r0+r)*512 + c0+cx]; }
  __syncthreads();
  #pragma unroll
  for (int i=0;i<4;i++){ int r = ry + i*8; out[(size_t)(c0+r)*512 + r0+cx] = f2b(t[cx][r]); }
}

// ---------------- batched precompute: 3x NT gemm -> bf16(acc*scale) ----------------
__global__ __launch_bounds__(128) void pregemm_k(
    const u16* __restrict__ A0, const u16* __restrict__ B0, u16* __restrict__ C0, float p0,
    const u16* __restrict__ A1, const u16* __restrict__ B1, u16* __restrict__ C1, float p1,
    const u16* __restrict__ A2, const u16* __restrict__ B2, u16* __restrict__ C2, float p2){
  const u16* A; const u16* Bm; u16* C; float sp;
  if (blockIdx.z==0){A=A0;Bm=B0;C=C0;sp=p0;}
  else if (blockIdx.z==1){A=A1;Bm=B1;C=C1;sp=p1;}
  else {A=A2;Bm=B2;C=C2;sp=p2;}
  int m0 = blockIdx.x*32 + (threadIdx.x>>6)*16;
  int n0 = blockIdx.y*64;
  int l = threadIdx.x & 63;
  int lr = l & 15, lk = (l>>4)*8;
  const u16* Arow = A + (size_t)(m0 + lr)*512 + lk;
  const u16* Bp   = Bm + (size_t)(n0 + lr)*512 + lk;
  f32x4 acc[4] = {};
  #pragma unroll
  for (int k0=0;k0<512;k0+=32){
    s16x8 a = *(const s16x8*)(Arow + k0);
    #pragma unroll
    for (int j=0;j<4;j++){
      s16x8 b = *(const s16x8*)(Bp + (size_t)j*16*512 + k0);
      acc[j] = __builtin_amdgcn_mfma_f32_16x16x32_bf16(a, b, acc[j], 0,0,0);
    }
  }
  int mbase = m0 + (l>>4)*4;
  #pragma unroll
  for (int j=0;j<4;j++){
    int n = n0 + j*16 + lr;
    #pragma unroll
    for (int r=0;r<4;r++)
      C[(size_t)(mbase+r)*512 + n] = f2b(acc[j][r] * sp);
  }
}

// ---------------- batched precompute: 4x matvec + bvw + dot2 ----------------
__global__ __launch_bounds__(256) void smalls_k(
    const float* __restrict__ qW, const float* __restrict__ kB, float* __restrict__ bq,
    const float* __restrict__ rqW, const float* __restrict__ rkB, float* __restrict__ bq_r,
    const float* __restrict__ kW, const float* __restrict__ qB, float* __restrict__ wcb,
    const float* __restrict__ rkW, const float* __restrict__ rqB, float* __restrict__ wcb_r,
    const float* __restrict__ wrW, const float* __restrict__ vB, float* __restrict__ bvw,
    float* __restrict__ cb0s){
  int blk = blockIdx.x;
  if (blk < 512){
    int which = blk >> 7;
    const float* W; const float* v; float* out;
    if (which==0){W=qW; v=kB; out=bq;}
    else if (which==1){W=rqW; v=rkB; out=bq_r;}
    else if (which==2){W=kW; v=qB; out=wcb;}
    else {W=rkW; v=rqB; out=wcb_r;}
    int i = (blk&127)*4 + (threadIdx.x>>6), l = threadIdx.x&63;
    const float* r = W + (size_t)i*512;
    float s = 0.f;
    #pragma unroll
    for (int k=0;k<8;k++) s += r[l + 64*k]*v[l + 64*k];
    #pragma unroll
    for (int off=32; off; off>>=1) s += __shfl_xor(s, off);
    if (l==0) out[i] = s * SCALE;
  } else if (blk < 514){
    int n = (blk-512)*256 + threadIdx.x;
    float s = 0.f;
    for (int o=0;o<512;o++) s += vB[o]*wrW[(size_t)o*512 + n];
    bvw[n] = s;
  } else {
    if (threadIdx.x < 128){
      int w = threadIdx.x>>6, l = threadIdx.x&63;
      const float* a = w ? rkB : kB;
      const float* bvec = w ? rqB : qB;
      float s = 0.f;
      #pragma unroll
      for (int k=0;k<8;k++) s += a[l + 64*k]*bvec[l + 64*k];
      #pragma unroll
      for (int off=32; off; off>>=1) s += __shfl_xor(s, off);
      if (l==0) cb0s[w] = s * SCALE;
    }
  }
}

// ---------------- memory init (fp32 + bf16 mirror) ----------------
__global__ __launch_bounds__(256) void meminit_k(const float* __restrict__ src,
    float* __restrict__ mem, u16* __restrict__ memh){
  int i = blockIdx.x*256 + threadIdx.x;
  float v = src[i & (SS*DM-1)];
  mem[i] = v;
  memh[i] = f2b(v);
}

// ---------------- mem = LN(0.9*mem + 0.1*w3) -> fp32 + bf16 mirror ----------------
__global__ __launch_bounds__(256) void mem_ln_k(float* __restrict__ mem, const float* __restrict__ w3,
    const float* __restrict__ g, const float* __restrict__ be, u16* __restrict__ memh){
  int row = blockIdx.x;
  int d = threadIdx.x;
  float* mrow = mem + (size_t)row*DM;
  const float* wrow = w3 + (size_t)row*DM;
  float x0 = 0.9f*mrow[d]     + 0.1f*wrow[d];
  float x1 = 0.9f*mrow[d+256] + 0.1f*wrow[d+256];
  float s1 = x0+x1, s2 = x0*x0 + x1*x1;
  s1 = wave_reduce_sum(s1); s2 = wave_reduce_sum(s2);
  __shared__ float r1[4], r2[4];
  int lane = d & 63, w = d>>6;
  if (lane==0){ r1[w]=s1; r2[w]=s2; }
  __syncthreads();
  float S1 = r1[0]+r1[1]+r1[2]+r1[3];
  float S2 = r2[0]+r2[1]+r2[2]+r2[3];
  float mu = S1 * (1.f/DM);
  float var = S2*(1.f/DM) - mu*mu;
  float rs = rsqrtf(var + 1e-5f);
  float y0 = (x0-mu)*rs*g[d] + be[d];
  float y1 = (x1-mu)*rs*g[d+256] + be[d+256];
  mrow[d] = y0; mrow[d+256] = y1;
  memh[(size_t)row*DM + d] = f2b(y0);
  memh[(size_t)row*DM + d+256] = f2b(y1);
}

// ---------------- masked token sum partials (vectorized, per-wave slices) ----------------
__global__ __launch_bounds__(256) void tokpart_k(const u16* __restrict__ tok,
    const int* __restrict__ mask, float* __restrict__ tp){
  int b = blockIdx.x, sl = blockIdx.y;
  int w = threadIdx.x>>6, l = threadIdx.x&63;
  float acc[8] = {};
  #pragma unroll 4
  for (int i=0;i<32;i++){
    int t = sl*128 + w + 4*i;
    float m = (float)mask[b*TT + t];
    s16x8 v = *(const s16x8*)(tok + ((size_t)(b*TT + t))*512 + l*8);
    #pragma unroll
    for (int e=0;e<8;e++) acc[e] += m*b2f((u16)v[e]);
  }
  float* dst = tp + ((size_t)(b*64 + sl*4 + w))*512 + l*8;
  #pragma unroll
  for (int e=0;e<8;e++) dst[e] = acc[e];
}

// ---------------- catden: cat[b][1024] = [tok_sum, ctx], denom[b] ----------------
__global__ __launch_bounds__(256) void catden_k(const float* __restrict__ tp,
    const float* __restrict__ rws, const float* __restrict__ rv,
    const int* __restrict__ mask, float* __restrict__ cat, float* __restrict__ denomv){
  int b = blockIdx.x, tid = threadIdx.x;
  float dn = 0.f;
  for (int t=tid; t<TT; t+=256) dn += (float)mask[b*TT+t];
  dn = wave_reduce_sum(dn);
  __shared__ float dred[4];
  if ((tid&63)==0) dred[tid>>6]=dn;
  #pragma unroll
  for (int it=0; it<2; ++it){
    int d = tid + it*256;
    float ts = 0.f;
    for (int k=0;k<64;k++) ts += tp[((size_t)(b*64+k))*512 + d];
    cat[(size_t)b*1024 + d] = ts;
    float c = 0.f;
    for (int s=0;s<SS;s++) c += rws[b*SS+s]*rv[((size_t)b*SS+s)*DM + d];
    cat[(size_t)b*1024 + 512 + d] = c;
  }
  __syncthreads();
  if (tid==0) denomv[b] = dred[0]+dred[1]+dred[2]+dred[3];
}

// ---------------- fuse: pooled[b][n0..n0+64] ----------------
__global__ __launch_bounds__(256) void fuse_k(const float* __restrict__ cat,
    const float* __restrict__ denomv, const float* __restrict__ fuseW,
    const float* __restrict__ fuseb, float* __restrict__ pooled){
  int b = blockIdx.x, n0 = blockIdx.y*64;
  int l = threadIdx.x&63, kc = threadIdx.x>>6;
  int n = n0 + l;
  float acc = 0.f;
  const float* crow = cat + (size_t)b*1024;
  for (int k=kc*256; k<kc*256+256; ++k)
    acc += crow[k]*fuseW[(size_t)k*512 + n];
  __shared__ float red[4][64];
  red[kc][l] = acc;
  __syncthreads();
  if (kc==0){
    float denom = denomv[b];
    float tot = red[0][l]+red[1][l]+red[2][l]+red[3][l];
    pooled[(size_t)b*512 + n] = (tot + denom*fuseb[n]) / fmaxf(denom, 1.f);
  }
}

// ---------------- cls: out[b][8] ----------------
__global__ __launch_bounds__(256) void cls_k(const float* __restrict__ pooled,
    const float* __restrict__ clsW, const float* __restrict__ clsb, float* __restrict__ out){
  int b = blockIdx.x;
  int c = threadIdx.x&7, kc = threadIdx.x>>3;
  float acc = 0.f;
  const float* prow = pooled + (size_t)b*512;
  for (int d=kc*16; d<kc*16+16; ++d) acc += prow[d]*clsW[d*8+c];
  __shared__ float red[32][8];
  red[kc][c] = acc;
  __syncthreads();
  if (threadIdx.x < 8){
    float tot = 0.f;
    #pragma unroll
    for (int k=0;k<32;k++) tot += red[k][threadIdx.x];
    out[b*8 + threadIdx.x] = tot + clsb[threadIdx.x];
  }
}

extern "C" void kernel_launch(void* const* d_in, const int* in_sizes, int n_in,
                              void* d_out, int out_size, void* d_ws, size_t ws_size,
                              hipStream_t stream){
  (void)in_sizes; (void)n_in; (void)out_size; (void)ws_size;
  const int*   ids   = (const int*)d_in[0];
  const int*   amask = (const int*)d_in[1];
  const float* temb  = (const float*)d_in[2];
  const float* pemb  = (const float*)d_in[3];
  const float* mem0  = (const float*)d_in[4];
  const float* qW=(const float*)d_in[5],  *qB=(const float*)d_in[6];
  const float* kW=(const float*)d_in[7],  *kB=(const float*)d_in[8];
  const float* vW=(const float*)d_in[9],  *vB=(const float*)d_in[10];
  const float* wrW=(const float*)d_in[11],*wrB=(const float*)d_in[12];
  const float* gtW=(const float*)d_in[13],*gtB=(const float*)d_in[14];
  const float* rqW=(const float*)d_in[15],*rqB=(const float*)d_in[16];
  const float* rkW=(const float*)d_in[17],*rkB=(const float*)d_in[18];
  const float* rvW=(const float*)d_in[19],*rvB=(const float*)d_in[20];
  const float* fW=(const float*)d_in[21], *fB=(const float*)d_in[22];
  const float* cW=(const float*)d_in[23], *cB=(const float*)d_in[24];
  const float* tg=(const float*)d_in[25], *tb=(const float*)d_in[26];
  const float* mg=(const float*)d_in[27], *mb=(const float*)d_in[28];

  // ---- workspace layout (~108 MB) ----
  char* p = (char*)d_ws;
  size_t off = 0;
  auto alloc = [&](size_t bytes)->char*{ char* r = p + off; off += (bytes + 255) & ~(size_t)255; return r; };
  u16*   tokens = (u16*)  alloc((size_t)BT*DM*2);        // 67.1 MB
  u16*   Pt     = (u16*)  alloc((size_t)BB*SS*DM*2);     // 2.1 MB
  u16*   BNDT   = (u16*)  alloc((size_t)BB*SS*TT*2);     // 8.4 MB
  float* cspart = (float*)alloc((size_t)BB*32*64*4);     // 0.26 MB
  float* wtpart = (float*)alloc((size_t)4*2048*512*4);   // 16.8 MB (hosts aliases)
  u16*   t1h    = (u16*)  alloc((size_t)2048*512*2);
  u16*   zh     = (u16*)  alloc((size_t)2048*512*2);
  float* mem    = (float*)alloc((size_t)BB*SS*DM*4);
  u16*   memh   = (u16*)  alloc((size_t)BB*SS*DM*2);
  u16*   wrWT   = (u16*)  alloc(512*512*2);
  u16*   gtWT   = (u16*)  alloc(512*512*2);
  u16*   rvWT   = (u16*)  alloc(512*512*2);
  u16*   WqkT   = (u16*)  alloc(512*512*2);
  u16*   WqkT_r = (u16*)  alloc(512*512*2);
  u16*   WvwT   = (u16*)  alloc(512*512*2);
  float* bq     = (float*)alloc(512*4);
  float* bq_r   = (float*)alloc(512*4);
  float* wcb    = (float*)alloc(512*4);
  float* wcb_r  = (float*)alloc(512*4);
  float* bvw    = (float*)alloc(512*4);
  float* cb0s   = (float*)alloc(256);
  float* cbuf   = (float*)alloc(2048*4);
  float* slot   = (float*)alloc(2048*4);
  float* rr     = (float*)alloc(2048*4);
  float* raw    = (float*)alloc(2048*4);
  float* catbuf = (float*)alloc((size_t)BB*1024*4);
  float* denomv = (float*)alloc(BB*4);
  float* pooled = (float*)alloc((size_t)BB*512*4);
  // aliases inside wtpart (liveness-disjoint):
  float* rv32   = wtpart;                       // read phase only (4 MB)
  float* tspart = wtpart + 1048576;             // read phase only (4 MB)
  float* gh32   = wtpart + 2097152;             // gate output, dead before next wt_k
  u16*   qWb    = (u16*)((char*)wtpart + 12582912);  // precompute only
  u16*   kWb    = qWb + 512*512;
  u16*   rqWb   = kWb + 512*512;
  u16*   rkWb   = rqWb + 512*512;
  u16*   vWb    = (u16*)((char*)wtpart + 14680064);  // precompute only

  // ---- precompute (6 dispatches) ----
  allconv_k<<<5120, 256, 0, stream>>>(qW, qWb, kW, kWb, rqW, rqWb, rkW, rkWb, vW, vWb);
  alltconv_k<<<dim3(16,16,3), 256, 0, stream>>>(wrW, wrWT, gtW, gtWT, rvW, rvWT);
  pregemm_k<<<dim3(16,8,3), 128, 0, stream>>>(qWb, kWb, WqkT, SCALE,
                                              rqWb, rkWb, WqkT_r, SCALE,
                                              wrWT, vWb, WvwT, 1.0f);
  smalls_k<<<515, 256, 0, stream>>>(qW, kB, bq, rqW, rkB, bq_r, kW, qB, wcb,
                                    rkW, rqB, wcb_r, wrW, vB, bvw, cb0s);
  embed_ln_k<<<BT/8, 256, 0, stream>>>(ids, temb, pemb, tg, tb, tokens);
  meminit_k<<<(BB*SS*DM)/256, 256, 0, stream>>>(mem0, mem, memh);

  // ---- recurrent steps (8 dispatches each) ----
  for (int step=0; step<NSTEPS; ++step){
    ptcb_k<<<dim3(64,9), 128, 0, stream>>>(memh, WqkT, bq, mem, wcb, cb0s, Pt, cbuf);
    bind_k<<<dim3(32,32), 64, 0, stream>>>(tokens, Pt, cbuf, amask, BNDT, cspart);
    csred_k<<<32, 64, 0, stream>>>(cspart, slot, rr, raw);
    wt_k<<<dim3(4,32,4), 256, 0, stream>>>(BNDT, tokens, wtpart);
    wtred_k<<<4096, 256, 0, stream>>>(wtpart, slot, t1h);
    ntgemm_k<5><<<dim3(64,8), 128, 0, stream>>>(t1h, WvwT, bvw, nullptr, rr, wrB, zh, 0.f);
    ntgemm_k<2><<<dim3(64,8), 128, 0, stream>>>(zh, gtWT, gtB, zh, nullptr, nullptr, gh32, 0.f);
    mem_ln_k<<<BB*SS, 256, 0, stream>>>(mem, gh32, mg, mb, memh);
  }

  // ---- read phase ----
  ptcb_k<<<dim3(64,9), 128, 0, stream>>>(memh, WqkT_r, bq_r, mem, wcb_r, cb0s+1, Pt, cbuf);
  bind_k<<<dim3(32,32), 64, 0, stream>>>(tokens, Pt, cbuf, amask, BNDT, cspart);
  csred_k<<<32, 64, 0, stream>>>(cspart, slot, rr, raw);
  ntgemm_k<3><<<dim3(64,8), 128, 0, stream>>>(memh, rvWT, rvB, nullptr, nullptr, nullptr, rv32, 0.f);
  tokpart_k<<<dim3(32,16), 256, 0, stream>>>(tokens, amask, tspart);
  catden_k<<<32, 256, 0, stream>>>(tspart, raw, rv32, amask, catbuf, denomv);
  fuse_k<<<dim3(32,8), 256, 0, stream>>>(catbuf, denomv, fW, fB, pooled);
  cls_k<<<32, 256, 0, stream>>>(pooled, cW, cB, (float*)d_out);
}